// Round 6
// baseline (8326.421 us; speedup 1.0000x reference)
//
#include <hip/hip_runtime.h>
#include <hip/hip_bf16.h>

// ---------------------------------------------------------------------------
// RecurrentAutoencoder on MI355X (gfx950).
// e1:   256 thr/block, 2 units/thread (halved LDS traffic), DPP quad ring.
// scan: SINGLE WAVE, zero barriers — wave-synchronous LDS h roundtrip.
// dec:  512-thread fused d1+d2, raw lgkm barrier.
// ---------------------------------------------------------------------------

typedef float v2f __attribute__((ext_vector_type(2)));

__device__ __forceinline__ v2f pk_fma(v2f a, v2f b, v2f c) {
  v2f d;
  asm("v_pk_fma_f32 %0, %1, %2, %3" : "=v"(d) : "v"(a), "v"(b), "v"(c));
  return d;
}

__device__ __forceinline__ float sigm(float x) {
  return 1.0f / (1.0f + __expf(-x));
}
__device__ __forceinline__ float tanh_fast(float x) {
  return 1.0f - 2.0f / (__expf(2.0f * x) + 1.0f);
}

// Raw workgroup barrier: waits LDS ops only, does NOT drain vmcnt.
__device__ __forceinline__ void wg_barrier() {
  asm volatile("s_waitcnt lgkmcnt(0)\n\ts_barrier" ::: "memory");
}
__device__ __forceinline__ void lds_fence() {
  asm volatile("s_waitcnt lgkmcnt(0)" ::: "memory");
}

template <int CTRL>
__device__ __forceinline__ float dppmv(float v) {
  return __int_as_float(__builtin_amdgcn_update_dpp(
      0, __float_as_int(v), CTRL, 0xF, 0xF, true));
}
#define DPP_XOR1   0xB1
#define DPP_XOR2   0x4E
#define DPP_ROT1   0x93   // quad rotate +1
#define DPP_HMIRR  0x141
#define DPP_MIRR   0x140

__device__ __forceinline__ int swzc(int k) { return k + ((k >> 5) << 2); }

#define A_BB 16

// ---------------------------------------------------------------------------
// Stage A. 256 threads = 4 waves. Thread: u16 = wave*16 + (lane>>2) in [0,64),
// q = lane&3. Owns units uA=u16 and uB=u16+64 (8 gate rows), k in [32q,+32),
// c-state for batches [4q,4q+4). DPP quad ring as rounds 2-5 (validated).
// ---------------------------------------------------------------------------
__global__ __launch_bounds__(256, 1) void lstm_e1_kernel(
    const float* __restrict__ x,     // [4096][140]
    const float* __restrict__ Wih,   // [512][1]
    const float* __restrict__ Whh,   // [512][128]
    const float* __restrict__ bih,   // [512]
    const float* __restrict__ bhh,   // [512]
    float* __restrict__ h1_out)      // [4096][128]
{
  const int j    = threadIdx.x;
  const int lane = j & 63;
  const int w    = j >> 6;
  const int u16  = w * 16 + (lane >> 2);  // 0..63
  const int q    = lane & 3;
  const int uA   = u16;
  const int uB   = u16 + 64;
  const int b0   = blockIdx.x * A_BB;

  __shared__ float Hs[2][A_BB][144];
  __shared__ float xs[2][A_BB];

  for (int i = j; i < A_BB * 144; i += 256) ((float*)Hs[0])[i] = 0.0f;
  if (j < A_BB) xs[0][j] = x[(b0 + j) * 140];

  // weights: 8 gate rows x 32 k = 256 VGPR (packed pairs)
  v2f wA[4][16], wB[4][16];
#pragma unroll
  for (int g = 0; g < 4; ++g)
#pragma unroll
    for (int k = 0; k < 32; k += 4) {
      const float4 a = *(const float4*)&Whh[(g * 128 + uA) * 128 + q * 32 + k];
      wA[g][k / 2 + 0].x = a.x; wA[g][k / 2 + 0].y = a.y;
      wA[g][k / 2 + 1].x = a.z; wA[g][k / 2 + 1].y = a.w;
      const float4 b = *(const float4*)&Whh[(g * 128 + uB) * 128 + q * 32 + k];
      wB[g][k / 2 + 0].x = b.x; wB[g][k / 2 + 0].y = b.y;
      wB[g][k / 2 + 1].x = b.z; wB[g][k / 2 + 1].y = b.w;
    }

  float wihA[4], bsA[4], wihB[4], bsB[4];
#pragma unroll
  for (int g = 0; g < 4; ++g) {
    wihA[g] = Wih[g * 128 + uA];
    bsA[g]  = bih[g * 128 + uA] + bhh[g * 128 + uA];
    wihB[g] = Wih[g * 128 + uB];
    bsB[g]  = bih[g * 128 + uB] + bhh[g * 128 + uB];
  }

  float cA[4] = {0,0,0,0}, hA[4] = {0,0,0,0};
  float cB[4] = {0,0,0,0}, hB[4] = {0,0,0,0};
  __syncthreads();

  int cur = 0;
  for (int t = 0; t < 140; ++t) {
    const int nxt = cur ^ 1;

    // issue x prefetch early; LDS write deferred to end of step
    float xnext = 0.0f;
    const bool do_x = (j < A_BB) && (t + 1) < 140;
    if (do_x) xnext = x[(b0 + j) * 140 + t + 1];

    v2f RA[4][4], RB[4][4];
#pragma unroll
    for (int g = 0; g < 4; ++g)
#pragma unroll
      for (int i = 0; i < 4; ++i) {
        RA[g][i].x = 0.f; RA[g][i].y = 0.f;
        RB[g][i].x = 0.f; RB[g][i].y = 0.f;
      }

#pragma unroll
    for (int s = 0; s < 4; ++s) {
      if (s) {
#pragma unroll
        for (int g = 0; g < 4; ++g)
#pragma unroll
          for (int i = 0; i < 4; ++i) {
            RA[g][i].x = dppmv<DPP_ROT1>(RA[g][i].x);
            RA[g][i].y = dppmv<DPP_ROT1>(RA[g][i].y);
            RB[g][i].x = dppmv<DPP_ROT1>(RB[g][i].x);
            RB[g][i].y = dppmv<DPP_ROT1>(RB[g][i].y);
          }
      }
      const int cch = (q - 1 - s) & 3;
      const float* hbase = &Hs[cur][cch * 4][q * 36];
#pragma unroll
      for (int i = 0; i < 4; ++i) {
        const float* hrow = hbase + i * 144;
#pragma unroll
        for (int kk = 0; kk < 8; ++kk) {
          const float4 hv = *(const float4*)&hrow[kk * 4];
          v2f h01; h01.x = hv.x; h01.y = hv.y;
          v2f h23; h23.x = hv.z; h23.y = hv.w;
#pragma unroll
          for (int g = 0; g < 4; ++g) {
            RA[g][i] = pk_fma(wA[g][2 * kk + 0], h01, RA[g][i]);
            RA[g][i] = pk_fma(wA[g][2 * kk + 1], h23, RA[g][i]);
            RB[g][i] = pk_fma(wB[g][2 * kk + 0], h01, RB[g][i]);
            RB[g][i] = pk_fma(wB[g][2 * kk + 1], h23, RB[g][i]);
          }
        }
      }
    }

    if (do_x) xs[nxt][j] = xnext;

    const float4 xv = *(const float4*)&xs[cur][q * 4];
    const float xa[4] = {xv.x, xv.y, xv.z, xv.w};
#pragma unroll
    for (int i = 0; i < 4; ++i) {
      {
        const float gi = sigm(RA[0][i].x + RA[0][i].y + __builtin_fmaf(wihA[0], xa[i], bsA[0]));
        const float gf = sigm(RA[1][i].x + RA[1][i].y + __builtin_fmaf(wihA[1], xa[i], bsA[1]));
        const float gg = tanh_fast(RA[2][i].x + RA[2][i].y + __builtin_fmaf(wihA[2], xa[i], bsA[2]));
        const float go = sigm(RA[3][i].x + RA[3][i].y + __builtin_fmaf(wihA[3], xa[i], bsA[3]));
        cA[i] = gf * cA[i] + gi * gg;
        hA[i] = go * tanh_fast(cA[i]);
        Hs[nxt][q * 4 + i][swzc(uA)] = hA[i];
      }
      {
        const float gi = sigm(RB[0][i].x + RB[0][i].y + __builtin_fmaf(wihB[0], xa[i], bsB[0]));
        const float gf = sigm(RB[1][i].x + RB[1][i].y + __builtin_fmaf(wihB[1], xa[i], bsB[1]));
        const float gg = tanh_fast(RB[2][i].x + RB[2][i].y + __builtin_fmaf(wihB[2], xa[i], bsB[2]));
        const float go = sigm(RB[3][i].x + RB[3][i].y + __builtin_fmaf(wihB[3], xa[i], bsB[3]));
        cB[i] = gf * cB[i] + gi * gg;
        hB[i] = go * tanh_fast(cB[i]);
        Hs[nxt][q * 4 + i][swzc(uB)] = hB[i];
      }
    }
    wg_barrier();
    cur = nxt;
  }

#pragma unroll
  for (int i = 0; i < 4; ++i) {
    h1_out[(b0 + q * 4 + i) * 128 + uA] = hA[i];
    h1_out[(b0 + q * 4 + i) * 128 + uB] = hB[i];
  }
}

// ---------------------------------------------------------------------------
// Stage B input projection, PERMUTED: Up[t][u] = (pre_i,pre_f,pre_g,pre_o).
// ---------------------------------------------------------------------------
__global__ __launch_bounds__(256, 1) void u_pre_kernel(
    const float* __restrict__ h1,   // [4096][128]
    const float* __restrict__ Wih,  // [256][128]
    const float* __restrict__ bih,  // [256]
    const float* __restrict__ bhh,  // [256]
    float* __restrict__ Up)         // [4096][64][4]
{
  const int t = blockIdx.x;
  const int j = threadIdx.x;      // gate row j = g*64 + u
  __shared__ float hs[128];
  if (j < 128) hs[j] = h1[t * 128 + j];
  __syncthreads();
  float acc = bih[j] + bhh[j];
#pragma unroll
  for (int k = 0; k < 128; k += 4) {
    const float4 hv = *(const float4*)&hs[k];
    const float4 wv = *(const float4*)&Wih[j * 128 + k];
    acc += wv.x * hv.x + wv.y * hv.y + wv.z * hv.z + wv.w * hv.w;
  }
  Up[t * 256 + (j & 63) * 4 + (j >> 6)] = acc;
}

// ---------------------------------------------------------------------------
// Stage B serial scan: SINGLE WAVE, ZERO BARRIERS. Lane = unit u in [0,64).
// Full K=64 dot per lane; weights 4x64 = 256 VGPR; h roundtrip through LDS is
// wave-synchronous (ds in-order + lgkmcnt). Up prefetched 4 steps deep.
// ---------------------------------------------------------------------------
__global__ __launch_bounds__(64, 1) void lstm_e2_scan_kernel(
    const float4* __restrict__ Up,  // [4096][64] of (i,f,g,o)
    const float* __restrict__ Whh,  // [256][64]
    float* __restrict__ z_out)      // [64]
{
  const int u = threadIdx.x;  // 0..63
  __shared__ float hbuf[64];

  // weights: 4 gates x 64 k packed = 256 VGPR
  v2f wr2[4][32];
#pragma unroll
  for (int g = 0; g < 4; ++g)
#pragma unroll
    for (int k = 0; k < 64; k += 4) {
      const float4 t4 = *(const float4*)&Whh[(g * 64 + u) * 64 + k];
      wr2[g][k / 2 + 0].x = t4.x; wr2[g][k / 2 + 0].y = t4.y;
      wr2[g][k / 2 + 1].x = t4.z; wr2[g][k / 2 + 1].y = t4.w;
    }

  float c = 0.0f, h = 0.0f;
  hbuf[u] = 0.0f;
  lds_fence();

  float4 U0 = Up[0 * 64 + u];
  float4 U1 = Up[1 * 64 + u];
  float4 U2 = Up[2 * 64 + u];
  float4 U3 = Up[3 * 64 + u];

  const float4* hb4 = (const float4*)hbuf;

#define SCAN_STEP(UREG, TNEXT)                                                \
  do {                                                                        \
    v2f A0, A1, A2, A3;                                                       \
    A0.x = 0.f; A0.y = 0.f; A1 = A0; A2 = A0; A3 = A0;                        \
    _Pragma("unroll")                                                         \
    for (int grp = 0; grp < 4; ++grp) {                                       \
      float4 Hh[4];                                                           \
      _Pragma("unroll")                                                       \
      for (int r = 0; r < 4; ++r) Hh[r] = hb4[grp * 4 + r];                   \
      _Pragma("unroll")                                                       \
      for (int r = 0; r < 4; ++r) {                                           \
        const int p = (grp * 4 + r) * 2;                                      \
        v2f hx; hx.x = Hh[r].x; hx.y = Hh[r].y;                               \
        v2f hy; hy.x = Hh[r].z; hy.y = Hh[r].w;                               \
        A0 = pk_fma(wr2[0][p], hx, A0); A0 = pk_fma(wr2[0][p + 1], hy, A0);   \
        A1 = pk_fma(wr2[1][p], hx, A1); A1 = pk_fma(wr2[1][p + 1], hy, A1);   \
        A2 = pk_fma(wr2[2][p], hx, A2); A2 = pk_fma(wr2[2][p + 1], hy, A2);   \
        A3 = pk_fma(wr2[3][p], hx, A3); A3 = pk_fma(wr2[3][p + 1], hy, A3);   \
      }                                                                       \
    }                                                                         \
    const float a0 = A0.x + A0.y, a1 = A1.x + A1.y;                           \
    const float a2 = A2.x + A2.y, a3 = A3.x + A3.y;                           \
    const float gi = sigm(a0 + UREG.x);                                       \
    const float gf = sigm(a1 + UREG.y);                                       \
    const float gg = tanh_fast(a2 + UREG.z);                                  \
    const float go = sigm(a3 + UREG.w);                                       \
    c = gf * c + gi * gg;                                                     \
    h = go * tanh_fast(c);                                                    \
    hbuf[u] = h;                                                              \
    {                                                                         \
      const int tp_ = ((TNEXT) < 4096) ? (TNEXT) : 4095;                      \
      UREG = Up[tp_ * 64 + u];                                                \
    }                                                                         \
    lds_fence();                                                              \
  } while (0)

#pragma unroll 1
  for (int t = 0; t < 4096; t += 4) {
    SCAN_STEP(U0, t + 4);
    SCAN_STEP(U1, t + 5);
    SCAN_STEP(U2, t + 6);
    SCAN_STEP(U3, t + 7);
  }
#undef SCAN_STEP

  z_out[u] = h;
}

// ---------------------------------------------------------------------------
// Stage C+D fused decoder. 512 threads; thread (u=j>>2, q=j&3) runs d1 with
// DPP quad reduce; wave 0 runs d2 (DPP butterfly + same-wave LDS broadcast).
// ---------------------------------------------------------------------------
__global__ __launch_bounds__(512, 1) void lstm_dec_kernel(
    const float* __restrict__ z,      // [64]
    const float* __restrict__ Wih1,   // [512][64]
    const float* __restrict__ Whh1,   // [512][128]
    const float* __restrict__ bih1,   // [512]
    const float* __restrict__ bhh1,   // [512]
    const float* __restrict__ Wih2,   // [4][128]
    const float* __restrict__ Whh2,   // [4][1]
    const float* __restrict__ bih2,   // [4]
    const float* __restrict__ bhh2,   // [4]
    float* __restrict__ out)          // [140]
{
  const int j = threadIdx.x;
  const int u = j >> 2;   // 0..127
  const int q = j & 3;

  __shared__ float hd[2][144];
  __shared__ float zs[64];
  __shared__ float act4[4];

  if (j < 64) zs[j] = z[j];
  if (j < 144) hd[0][j] = 0.0f;
  __syncthreads();

  float wr[4][32];
#pragma unroll
  for (int g = 0; g < 4; ++g)
#pragma unroll
    for (int k = 0; k < 32; k += 4)
      *(float4*)&wr[g][k] = *(const float4*)&Whh1[(g * 128 + u) * 128 + q * 32 + k];

  float pre0[4];
#pragma unroll
  for (int g = 0; g < 4; ++g) {
    float acc = bih1[g * 128 + u] + bhh1[g * 128 + u];
#pragma unroll
    for (int k = 0; k < 64; k += 4) {
      const float4 zv = *(const float4*)&zs[k];
      const float4 wv = *(const float4*)&Wih1[(g * 128 + u) * 64 + k];
      acc += wv.x * zv.x + wv.y * zv.y + wv.z * zv.z + wv.w * zv.w;
    }
    pre0[g] = acc;
  }

  const int g2  = j >> 4;
  const int i16 = j & 15;
  float w2d[8] = {0,0,0,0,0,0,0,0};
  if (j < 64) {
#pragma unroll
    for (int e = 0; e < 8; ++e) w2d[e] = Wih2[g2 * 128 + i16 * 8 + e];
  }
  const float bb2_0 = bih2[0] + bhh2[0], wh2_0 = Whh2[0];
  const float bb2_1 = bih2[1] + bhh2[1], wh2_1 = Whh2[1];
  const float bb2_2 = bih2[2] + bhh2[2], wh2_2 = Whh2[2];
  const float bb2_3 = bih2[3] + bhh2[3], wh2_3 = Whh2[3];

  float c1 = 0.0f;
  float c2 = 0.0f, h2 = 0.0f;

  int cur = 0;
  for (int t = 0; t < 140; ++t) {
    float a0 = 0.f, a1 = 0.f, a2 = 0.f, a3 = 0.f;
#pragma unroll
    for (int kk = 0; kk < 8; ++kk) {
      const float4 hv = *(const float4*)&hd[cur][q * 36 + kk * 4];
      a0 = __builtin_fmaf(wr[0][kk*4+0], hv.x, a0); a0 = __builtin_fmaf(wr[0][kk*4+1], hv.y, a0);
      a0 = __builtin_fmaf(wr[0][kk*4+2], hv.z, a0); a0 = __builtin_fmaf(wr[0][kk*4+3], hv.w, a0);
      a1 = __builtin_fmaf(wr[1][kk*4+0], hv.x, a1); a1 = __builtin_fmaf(wr[1][kk*4+1], hv.y, a1);
      a1 = __builtin_fmaf(wr[1][kk*4+2], hv.z, a1); a1 = __builtin_fmaf(wr[1][kk*4+3], hv.w, a1);
      a2 = __builtin_fmaf(wr[2][kk*4+0], hv.x, a2); a2 = __builtin_fmaf(wr[2][kk*4+1], hv.y, a2);
      a2 = __builtin_fmaf(wr[2][kk*4+2], hv.z, a2); a2 = __builtin_fmaf(wr[2][kk*4+3], hv.w, a2);
      a3 = __builtin_fmaf(wr[3][kk*4+0], hv.x, a3); a3 = __builtin_fmaf(wr[3][kk*4+1], hv.y, a3);
      a3 = __builtin_fmaf(wr[3][kk*4+2], hv.z, a3); a3 = __builtin_fmaf(wr[3][kk*4+3], hv.w, a3);
    }
    a0 += dppmv<DPP_XOR1>(a0); a0 += dppmv<DPP_XOR2>(a0);
    a1 += dppmv<DPP_XOR1>(a1); a1 += dppmv<DPP_XOR2>(a1);
    a2 += dppmv<DPP_XOR1>(a2); a2 += dppmv<DPP_XOR2>(a2);
    a3 += dppmv<DPP_XOR1>(a3); a3 += dppmv<DPP_XOR2>(a3);

    const float gi = sigm(a0 + pre0[0]);
    const float gf = sigm(a1 + pre0[1]);
    const float gg = tanh_fast(a2 + pre0[2]);
    const float go = sigm(a3 + pre0[3]);
    c1 = gf * c1 + gi * gg;
    const float h1v = go * tanh_fast(c1);
    if (q == 0) hd[cur ^ 1][swzc(u)] = h1v;
    wg_barrier();
    cur ^= 1;

    if (j < 64) {
      const int kb = i16 * 8;
      const float4 hA = *(const float4*)&hd[cur][swzc(kb)];
      const float4 hB = *(const float4*)&hd[cur][swzc(kb) + 4];
      float p = hA.x * w2d[0];
      p = __builtin_fmaf(hA.y, w2d[1], p);
      p = __builtin_fmaf(hA.z, w2d[2], p);
      p = __builtin_fmaf(hA.w, w2d[3], p);
      p = __builtin_fmaf(hB.x, w2d[4], p);
      p = __builtin_fmaf(hB.y, w2d[5], p);
      p = __builtin_fmaf(hB.z, w2d[6], p);
      p = __builtin_fmaf(hB.w, w2d[7], p);
      p += dppmv<DPP_XOR1>(p);
      p += dppmv<DPP_XOR2>(p);
      p += dppmv<DPP_HMIRR>(p);
      p += dppmv<DPP_MIRR>(p);
      if (i16 == 0) act4[g2] = p;
      const float4 acts = *(const float4*)&act4[0];  // same-wave, lgkm-ordered
      const float gi2 = sigm(acts.x + bb2_0 + wh2_0 * h2);
      const float gf2 = sigm(acts.y + bb2_1 + wh2_1 * h2);
      const float gg2 = tanh_fast(acts.z + bb2_2 + wh2_2 * h2);
      const float go2 = sigm(acts.w + bb2_3 + wh2_3 * h2);
      c2 = gf2 * c2 + gi2 * gg2;
      h2 = go2 * tanh_fast(c2);
      if (j == 0) out[t] = h2;
    }
  }
}

// ---------------------------------------------------------------------------
extern "C" void kernel_launch(void* const* d_in, const int* in_sizes, int n_in,
                              void* d_out, int out_size, void* d_ws, size_t ws_size,
                              hipStream_t stream) {
  const float* x      = (const float*)d_in[0];
  const float* Wih_e1 = (const float*)d_in[1];
  const float* Whh_e1 = (const float*)d_in[2];
  const float* bih_e1 = (const float*)d_in[3];
  const float* bhh_e1 = (const float*)d_in[4];
  const float* Wih_e2 = (const float*)d_in[5];
  const float* Whh_e2 = (const float*)d_in[6];
  const float* bih_e2 = (const float*)d_in[7];
  const float* bhh_e2 = (const float*)d_in[8];
  const float* Wih_d1 = (const float*)d_in[9];
  const float* Whh_d1 = (const float*)d_in[10];
  const float* bih_d1 = (const float*)d_in[11];
  const float* bhh_d1 = (const float*)d_in[12];
  const float* Wih_d2 = (const float*)d_in[13];
  const float* Whh_d2 = (const float*)d_in[14];
  const float* bih_d2 = (const float*)d_in[15];
  const float* bhh_d2 = (const float*)d_in[16];

  float* out = (float*)d_out;  // 140 floats

  float* h1 = (float*)d_ws;              // 4096*128
  float* Up = h1 + 4096 * 128;           // 4096*256 (permuted [t][u][gate])
  float* zb = Up + 4096 * 256;           // 64

  lstm_e1_kernel<<<4096 / A_BB, 256, 0, stream>>>(x, Wih_e1, Whh_e1, bih_e1, bhh_e1, h1);
  u_pre_kernel<<<4096, 256, 0, stream>>>(h1, Wih_e2, bih_e2, bhh_e2, Up);
  lstm_e2_scan_kernel<<<1, 64, 0, stream>>>((const float4*)Up, Whh_e2, zb);
  lstm_dec_kernel<<<1, 512, 0, stream>>>(zb, Wih_d1, Whh_d1, bih_d1, bhh_d1,
                                         Wih_d2, Whh_d2, bih_d2, bhh_d2, out);
}

// Round 7
// 3423.935 us; speedup vs baseline: 2.4318x; 2.4318x over previous
//
#include <hip/hip_runtime.h>
#include <hip/hip_bf16.h>

// ---------------------------------------------------------------------------
// RecurrentAutoencoder on MI355X (gfx950).
// e1:   round-5 known-good (512 thr, pk_fma, DPP quad ring, ~200 VGPR).
// scan: 2 waves / 128 thr, 128-VGPR weights (NO spill), pair DPP reduce,
//       one raw barrier per step. Tests wave-barrier-event cost model.
// dec:  512-thread fused d1+d2 (known-good).
// HARD CONSTRAINT LEARNED (r6): VALU-addressable VGPRs cap at 256/wave;
// keep per-thread register working set <= ~200.
// ---------------------------------------------------------------------------

typedef float v2f __attribute__((ext_vector_type(2)));

__device__ __forceinline__ v2f pk_fma(v2f a, v2f b, v2f c) {
  v2f d;
  asm("v_pk_fma_f32 %0, %1, %2, %3" : "=v"(d) : "v"(a), "v"(b), "v"(c));
  return d;
}

__device__ __forceinline__ float sigm(float x) {
  return 1.0f / (1.0f + __expf(-x));
}
__device__ __forceinline__ float tanh_fast(float x) {
  return 1.0f - 2.0f / (__expf(2.0f * x) + 1.0f);
}

// Raw workgroup barrier: waits LDS ops only, does NOT drain vmcnt.
__device__ __forceinline__ void wg_barrier() {
  asm volatile("s_waitcnt lgkmcnt(0)\n\ts_barrier" ::: "memory");
}

template <int CTRL>
__device__ __forceinline__ float dppmv(float v) {
  return __int_as_float(__builtin_amdgcn_update_dpp(
      0, __float_as_int(v), CTRL, 0xF, 0xF, true));
}
#define DPP_XOR1   0xB1
#define DPP_XOR2   0x4E
#define DPP_ROT1   0x93   // quad rotate: dest q <- (q-1)&3
#define DPP_HMIRR  0x141
#define DPP_MIRR   0x140

__device__ __forceinline__ int swzc(int k) { return k + ((k >> 5) << 2); }

#define A_BB 16

// ---------------------------------------------------------------------------
// Stage A (round-5 exact). 512 threads = 8 waves. Thread: u = wave*16 +
// (lane>>2) in [0,128), q = lane&3. Owns gate rows {u,128+u,256+u,384+u},
// k in [32q,32q+32), c-state of unit u for batches [4q,4q+4). DPP quad ring.
// ---------------------------------------------------------------------------
__global__ __launch_bounds__(512, 2) void lstm_e1_kernel(
    const float* __restrict__ x,     // [4096][140]
    const float* __restrict__ Wih,   // [512][1]
    const float* __restrict__ Whh,   // [512][128]
    const float* __restrict__ bih,   // [512]
    const float* __restrict__ bhh,   // [512]
    float* __restrict__ h1_out)      // [4096][128]
{
  const int j    = threadIdx.x;
  const int lane = j & 63;
  const int w    = j >> 6;
  const int u    = w * 16 + (lane >> 2);  // 0..127
  const int q    = lane & 3;
  const int b0   = blockIdx.x * A_BB;

  __shared__ float Hs[2][A_BB][144];
  __shared__ float xs[2][A_BB];

  for (int i = j; i < A_BB * 144; i += 512) ((float*)Hs[0])[i] = 0.0f;
  if (j < A_BB) xs[0][j] = x[(b0 + j) * 140];

  // weights: 4 gate rows x 32 k packed = 128 VGPR
  v2f wr2[4][16];
#pragma unroll
  for (int g = 0; g < 4; ++g)
#pragma unroll
    for (int k = 0; k < 32; k += 4) {
      const float4 t4 = *(const float4*)&Whh[(g * 128 + u) * 128 + q * 32 + k];
      wr2[g][k / 2 + 0].x = t4.x; wr2[g][k / 2 + 0].y = t4.y;
      wr2[g][k / 2 + 1].x = t4.z; wr2[g][k / 2 + 1].y = t4.w;
    }

  float wih[4], bs[4];
#pragma unroll
  for (int g = 0; g < 4; ++g) {
    wih[g] = Wih[g * 128 + u];
    bs[g]  = bih[g * 128 + u] + bhh[g * 128 + u];
  }

  float c[4]  = {0.f, 0.f, 0.f, 0.f};
  float hr[4] = {0.f, 0.f, 0.f, 0.f};
  __syncthreads();

  int cur = 0;
  for (int t = 0; t < 140; ++t) {
    const int nxt = cur ^ 1;

    v2f R2[4][4];
#pragma unroll
    for (int g = 0; g < 4; ++g)
#pragma unroll
      for (int i = 0; i < 4; ++i) { R2[g][i].x = 0.f; R2[g][i].y = 0.f; }

#pragma unroll
    for (int s = 0; s < 4; ++s) {
      if (s) {
#pragma unroll
        for (int g = 0; g < 4; ++g)
#pragma unroll
          for (int i = 0; i < 4; ++i) {
            R2[g][i].x = dppmv<DPP_ROT1>(R2[g][i].x);
            R2[g][i].y = dppmv<DPP_ROT1>(R2[g][i].y);
          }
      }
      const int cch = (q - 1 - s) & 3;  // batch chunk visited this stage
      const float* hbase = &Hs[cur][cch * 4][q * 36];
#pragma unroll
      for (int i = 0; i < 4; ++i) {
        const float* hrow = hbase + i * 144;
#pragma unroll
        for (int kk = 0; kk < 8; ++kk) {
          const float4 hv = *(const float4*)&hrow[kk * 4];
          v2f h01; h01.x = hv.x; h01.y = hv.y;
          v2f h23; h23.x = hv.z; h23.y = hv.w;
#pragma unroll
          for (int g = 0; g < 4; ++g) {
            R2[g][i] = pk_fma(wr2[g][2 * kk + 0], h01, R2[g][i]);
            R2[g][i] = pk_fma(wr2[g][2 * kk + 1], h23, R2[g][i]);
          }
        }
      }
    }

    if (j < A_BB && (t + 1) < 140) xs[nxt][j] = x[(b0 + j) * 140 + t + 1];

    const float4 xv = *(const float4*)&xs[cur][q * 4];
    const float xa[4] = {xv.x, xv.y, xv.z, xv.w};
#pragma unroll
    for (int i = 0; i < 4; ++i) {
      const float gi = sigm(R2[0][i].x + R2[0][i].y + __builtin_fmaf(wih[0], xa[i], bs[0]));
      const float gf = sigm(R2[1][i].x + R2[1][i].y + __builtin_fmaf(wih[1], xa[i], bs[1]));
      const float gg = tanh_fast(R2[2][i].x + R2[2][i].y + __builtin_fmaf(wih[2], xa[i], bs[2]));
      const float go = sigm(R2[3][i].x + R2[3][i].y + __builtin_fmaf(wih[3], xa[i], bs[3]));
      c[i]  = gf * c[i] + gi * gg;
      hr[i] = go * tanh_fast(c[i]);
      Hs[nxt][q * 4 + i][swzc(u)] = hr[i];
    }
    wg_barrier();
    cur = nxt;
  }

#pragma unroll
  for (int i = 0; i < 4; ++i)
    h1_out[(b0 + q * 4 + i) * 128 + u] = hr[i];
}

// ---------------------------------------------------------------------------
// Stage B input projection, PERMUTED: Up[t][u] = (pre_i,pre_f,pre_g,pre_o).
// ---------------------------------------------------------------------------
__global__ __launch_bounds__(256, 1) void u_pre_kernel(
    const float* __restrict__ h1,   // [4096][128]
    const float* __restrict__ Wih,  // [256][128]
    const float* __restrict__ bih,  // [256]
    const float* __restrict__ bhh,  // [256]
    float* __restrict__ Up)         // [4096][64][4]
{
  const int t = blockIdx.x;
  const int j = threadIdx.x;      // gate row j = g*64 + u
  __shared__ float hs[128];
  if (j < 128) hs[j] = h1[t * 128 + j];
  __syncthreads();
  float acc = bih[j] + bhh[j];
#pragma unroll
  for (int k = 0; k < 128; k += 4) {
    const float4 hv = *(const float4*)&hs[k];
    const float4 wv = *(const float4*)&Wih[j * 128 + k];
    acc += wv.x * hv.x + wv.y * hv.y + wv.z * hv.z + wv.w * hv.w;
  }
  Up[t * 256 + (j & 63) * 4 + (j >> 6)] = acc;
}

// ---------------------------------------------------------------------------
// Stage B serial scan: 128 threads = 2 waves. Thread (u = j>>1, p = j&1) owns
// all 4 gate rows of unit u over k-half [32p, 32p+32): 128 VGPR weights, NO
// spill. Pair reduce = one DPP_XOR1 per gate. One raw barrier per step.
// Up prefetched 2 steps deep (counted vmcnt, never drained at barrier).
// ---------------------------------------------------------------------------
__global__ __launch_bounds__(128, 1) void lstm_e2_scan_kernel(
    const float4* __restrict__ Up,  // [4096][64] of (i,f,g,o)
    const float* __restrict__ Whh,  // [256][64]
    float* __restrict__ z_out)      // [64]
{
  const int j = threadIdx.x;
  const int u = j >> 1;   // 0..63
  const int p = j & 1;    // k-half

  __shared__ float hb[2][64];

  // weights: 4 gates x 32 k packed = 128 VGPR
  v2f wr2[4][16];
#pragma unroll
  for (int g = 0; g < 4; ++g)
#pragma unroll
    for (int k = 0; k < 32; k += 4) {
      const float4 t4 = *(const float4*)&Whh[(g * 64 + u) * 64 + p * 32 + k];
      wr2[g][k / 2 + 0].x = t4.x; wr2[g][k / 2 + 0].y = t4.y;
      wr2[g][k / 2 + 1].x = t4.z; wr2[g][k / 2 + 1].y = t4.w;
    }

  if (j < 64) hb[0][j] = 0.0f;
  float c = 0.0f, h = 0.0f;

  float4 U0 = Up[0 * 64 + u];   // t = 0
  float4 U1 = Up[1 * 64 + u];   // t = 1
  __syncthreads();

  int cur = 0;
#pragma unroll 1
  for (int t = 0; t < 4096; t += 2) {
#pragma unroll
    for (int half = 0; half < 2; ++half) {
      const int tp = (t + 2 + half < 4096) ? (t + 2 + half) : 4095;
      const float4 Unew = Up[tp * 64 + u];
      const float4 Ucur = half ? U1 : U0;

      const float* hrow = &hb[cur][p * 32];
      v2f A0, A1, A2, A3;
      A0.x = 0.f; A0.y = 0.f; A1 = A0; A2 = A0; A3 = A0;
#pragma unroll
      for (int kk = 0; kk < 8; ++kk) {
        const float4 hv = *(const float4*)&hrow[kk * 4];
        v2f hx; hx.x = hv.x; hx.y = hv.y;
        v2f hy; hy.x = hv.z; hy.y = hv.w;
        A0 = pk_fma(wr2[0][2 * kk], hx, A0); A0 = pk_fma(wr2[0][2 * kk + 1], hy, A0);
        A1 = pk_fma(wr2[1][2 * kk], hx, A1); A1 = pk_fma(wr2[1][2 * kk + 1], hy, A1);
        A2 = pk_fma(wr2[2][2 * kk], hx, A2); A2 = pk_fma(wr2[2][2 * kk + 1], hy, A2);
        A3 = pk_fma(wr2[3][2 * kk], hx, A3); A3 = pk_fma(wr2[3][2 * kk + 1], hy, A3);
      }
      float a0 = A0.x + A0.y, a1 = A1.x + A1.y;
      float a2 = A2.x + A2.y, a3 = A3.x + A3.y;
      // pair reduce: lanes (2u, 2u+1) in the same quad
      a0 += dppmv<DPP_XOR1>(a0);
      a1 += dppmv<DPP_XOR1>(a1);
      a2 += dppmv<DPP_XOR1>(a2);
      a3 += dppmv<DPP_XOR1>(a3);

      const float gi = sigm(a0 + Ucur.x);
      const float gf = sigm(a1 + Ucur.y);
      const float gg = tanh_fast(a2 + Ucur.z);
      const float go = sigm(a3 + Ucur.w);
      c = gf * c + gi * gg;
      h = go * tanh_fast(c);
      if (p == 0) hb[cur ^ 1][u] = h;
      if (half) U1 = Unew; else U0 = Unew;
      wg_barrier();
      cur ^= 1;
    }
  }
  if (p == 0) z_out[u] = h;
}

// ---------------------------------------------------------------------------
// Stage C+D fused decoder. 512 threads; thread (u=j>>2, q=j&3) runs d1 with
// DPP quad reduce; wave 0 runs d2 (DPP butterfly + same-wave LDS broadcast).
// ---------------------------------------------------------------------------
__global__ __launch_bounds__(512, 1) void lstm_dec_kernel(
    const float* __restrict__ z,      // [64]
    const float* __restrict__ Wih1,   // [512][64]
    const float* __restrict__ Whh1,   // [512][128]
    const float* __restrict__ bih1,   // [512]
    const float* __restrict__ bhh1,   // [512]
    const float* __restrict__ Wih2,   // [4][128]
    const float* __restrict__ Whh2,   // [4][1]
    const float* __restrict__ bih2,   // [4]
    const float* __restrict__ bhh2,   // [4]
    float* __restrict__ out)          // [140]
{
  const int j = threadIdx.x;
  const int u = j >> 2;   // 0..127
  const int q = j & 3;

  __shared__ float hd[2][144];
  __shared__ float zs[64];
  __shared__ float act4[4];

  if (j < 64) zs[j] = z[j];
  if (j < 144) hd[0][j] = 0.0f;
  __syncthreads();

  float wr[4][32];
#pragma unroll
  for (int g = 0; g < 4; ++g)
#pragma unroll
    for (int k = 0; k < 32; k += 4)
      *(float4*)&wr[g][k] = *(const float4*)&Whh1[(g * 128 + u) * 128 + q * 32 + k];

  float pre0[4];
#pragma unroll
  for (int g = 0; g < 4; ++g) {
    float acc = bih1[g * 128 + u] + bhh1[g * 128 + u];
#pragma unroll
    for (int k = 0; k < 64; k += 4) {
      const float4 zv = *(const float4*)&zs[k];
      const float4 wv = *(const float4*)&Wih1[(g * 128 + u) * 64 + k];
      acc += wv.x * zv.x + wv.y * zv.y + wv.z * zv.z + wv.w * zv.w;
    }
    pre0[g] = acc;
  }

  const int g2  = j >> 4;
  const int i16 = j & 15;
  float w2d[8] = {0,0,0,0,0,0,0,0};
  if (j < 64) {
#pragma unroll
    for (int e = 0; e < 8; ++e) w2d[e] = Wih2[g2 * 128 + i16 * 8 + e];
  }
  const float bb2_0 = bih2[0] + bhh2[0], wh2_0 = Whh2[0];
  const float bb2_1 = bih2[1] + bhh2[1], wh2_1 = Whh2[1];
  const float bb2_2 = bih2[2] + bhh2[2], wh2_2 = Whh2[2];
  const float bb2_3 = bih2[3] + bhh2[3], wh2_3 = Whh2[3];

  float c1 = 0.0f;
  float c2 = 0.0f, h2 = 0.0f;

  int cur = 0;
  for (int t = 0; t < 140; ++t) {
    float a0 = 0.f, a1 = 0.f, a2 = 0.f, a3 = 0.f;
#pragma unroll
    for (int kk = 0; kk < 8; ++kk) {
      const float4 hv = *(const float4*)&hd[cur][q * 36 + kk * 4];
      a0 = __builtin_fmaf(wr[0][kk*4+0], hv.x, a0); a0 = __builtin_fmaf(wr[0][kk*4+1], hv.y, a0);
      a0 = __builtin_fmaf(wr[0][kk*4+2], hv.z, a0); a0 = __builtin_fmaf(wr[0][kk*4+3], hv.w, a0);
      a1 = __builtin_fmaf(wr[1][kk*4+0], hv.x, a1); a1 = __builtin_fmaf(wr[1][kk*4+1], hv.y, a1);
      a1 = __builtin_fmaf(wr[1][kk*4+2], hv.z, a1); a1 = __builtin_fmaf(wr[1][kk*4+3], hv.w, a1);
      a2 = __builtin_fmaf(wr[2][kk*4+0], hv.x, a2); a2 = __builtin_fmaf(wr[2][kk*4+1], hv.y, a2);
      a2 = __builtin_fmaf(wr[2][kk*4+2], hv.z, a2); a2 = __builtin_fmaf(wr[2][kk*4+3], hv.w, a2);
      a3 = __builtin_fmaf(wr[3][kk*4+0], hv.x, a3); a3 = __builtin_fmaf(wr[3][kk*4+1], hv.y, a3);
      a3 = __builtin_fmaf(wr[3][kk*4+2], hv.z, a3); a3 = __builtin_fmaf(wr[3][kk*4+3], hv.w, a3);
    }
    a0 += dppmv<DPP_XOR1>(a0); a0 += dppmv<DPP_XOR2>(a0);
    a1 += dppmv<DPP_XOR1>(a1); a1 += dppmv<DPP_XOR2>(a1);
    a2 += dppmv<DPP_XOR1>(a2); a2 += dppmv<DPP_XOR2>(a2);
    a3 += dppmv<DPP_XOR1>(a3); a3 += dppmv<DPP_XOR2>(a3);

    const float gi = sigm(a0 + pre0[0]);
    const float gf = sigm(a1 + pre0[1]);
    const float gg = tanh_fast(a2 + pre0[2]);
    const float go = sigm(a3 + pre0[3]);
    c1 = gf * c1 + gi * gg;
    const float h1v = go * tanh_fast(c1);
    if (q == 0) hd[cur ^ 1][swzc(u)] = h1v;
    wg_barrier();
    cur ^= 1;

    if (j < 64) {
      const int kb = i16 * 8;
      const float4 hA = *(const float4*)&hd[cur][swzc(kb)];
      const float4 hB = *(const float4*)&hd[cur][swzc(kb) + 4];
      float p = hA.x * w2d[0];
      p = __builtin_fmaf(hA.y, w2d[1], p);
      p = __builtin_fmaf(hA.z, w2d[2], p);
      p = __builtin_fmaf(hA.w, w2d[3], p);
      p = __builtin_fmaf(hB.x, w2d[4], p);
      p = __builtin_fmaf(hB.y, w2d[5], p);
      p = __builtin_fmaf(hB.z, w2d[6], p);
      p = __builtin_fmaf(hB.w, w2d[7], p);
      p += dppmv<DPP_XOR1>(p);
      p += dppmv<DPP_XOR2>(p);
      p += dppmv<DPP_HMIRR>(p);
      p += dppmv<DPP_MIRR>(p);
      if (i16 == 0) act4[g2] = p;
      const float4 acts = *(const float4*)&act4[0];  // same-wave, lgkm-ordered
      const float gi2 = sigm(acts.x + bb2_0 + wh2_0 * h2);
      const float gf2 = sigm(acts.y + bb2_1 + wh2_1 * h2);
      const float gg2 = tanh_fast(acts.z + bb2_2 + wh2_2 * h2);
      const float go2 = sigm(acts.w + bb2_3 + wh2_3 * h2);
      c2 = gf2 * c2 + gi2 * gg2;
      h2 = go2 * tanh_fast(c2);
      if (j == 0) out[t] = h2;
    }
  }
}

// ---------------------------------------------------------------------------
extern "C" void kernel_launch(void* const* d_in, const int* in_sizes, int n_in,
                              void* d_out, int out_size, void* d_ws, size_t ws_size,
                              hipStream_t stream) {
  const float* x      = (const float*)d_in[0];
  const float* Wih_e1 = (const float*)d_in[1];
  const float* Whh_e1 = (const float*)d_in[2];
  const float* bih_e1 = (const float*)d_in[3];
  const float* bhh_e1 = (const float*)d_in[4];
  const float* Wih_e2 = (const float*)d_in[5];
  const float* Whh_e2 = (const float*)d_in[6];
  const float* bih_e2 = (const float*)d_in[7];
  const float* bhh_e2 = (const float*)d_in[8];
  const float* Wih_d1 = (const float*)d_in[9];
  const float* Whh_d1 = (const float*)d_in[10];
  const float* bih_d1 = (const float*)d_in[11];
  const float* bhh_d1 = (const float*)d_in[12];
  const float* Wih_d2 = (const float*)d_in[13];
  const float* Whh_d2 = (const float*)d_in[14];
  const float* bih_d2 = (const float*)d_in[15];
  const float* bhh_d2 = (const float*)d_in[16];

  float* out = (float*)d_out;  // 140 floats

  float* h1 = (float*)d_ws;              // 4096*128
  float* Up = h1 + 4096 * 128;           // 4096*256 (permuted [t][u][gate])
  float* zb = Up + 4096 * 256;           // 64

  lstm_e1_kernel<<<4096 / A_BB, 512, 0, stream>>>(x, Wih_e1, Whh_e1, bih_e1, bhh_e1, h1);
  u_pre_kernel<<<4096, 256, 0, stream>>>(h1, Wih_e2, bih_e2, bhh_e2, Up);
  lstm_e2_scan_kernel<<<1, 128, 0, stream>>>((const float4*)Up, Whh_e2, zb);
  lstm_dec_kernel<<<1, 512, 0, stream>>>(zb, Wih_d1, Whh_d1, bih_d1, bhh_d1,
                                         Wih_d2, Whh_d2, bih_d2, bhh_d2, out);
}

// Round 8
// 3418.580 us; speedup vs baseline: 2.4356x; 1.0016x over previous
//
#include <hip/hip_runtime.h>
#include <hip/hip_bf16.h>

// ---------------------------------------------------------------------------
// RecurrentAutoencoder on MI355X (gfx950).
// e1:   known-good (512 thr, pk_fma, DPP quad ring).
// scan+dec: FUSED, covered by low-duty-cycle burner WGs on all CUs.
//   Hypothesis under test: single-WG phases run at ~1 GHz (low DPM state);
//   resident-but-sleeping waves on all CUs should lift gfxclk to ~2.4 GHz
//   without tripping the power cap (r5's max-rate burners did trip it).
// Scan body = round-7 exact (2 waves, 128-VGPR weights, pair DPP reduce,
// one raw barrier/step). Waves 2-7 run a barrier-matching idle loop, then
// all 8 waves run the round-5-validated dec phase.
// ---------------------------------------------------------------------------

typedef float v2f __attribute__((ext_vector_type(2)));

__device__ __forceinline__ v2f pk_fma(v2f a, v2f b, v2f c) {
  v2f d;
  asm("v_pk_fma_f32 %0, %1, %2, %3" : "=v"(d) : "v"(a), "v"(b), "v"(c));
  return d;
}

__device__ __forceinline__ float sigm(float x) {
  return 1.0f / (1.0f + __expf(-x));
}
__device__ __forceinline__ float tanh_fast(float x) {
  return 1.0f - 2.0f / (__expf(2.0f * x) + 1.0f);
}

// Raw workgroup barrier: waits LDS ops only, does NOT drain vmcnt.
__device__ __forceinline__ void wg_barrier() {
  asm volatile("s_waitcnt lgkmcnt(0)\n\ts_barrier" ::: "memory");
}

template <int CTRL>
__device__ __forceinline__ float dppmv(float v) {
  return __int_as_float(__builtin_amdgcn_update_dpp(
      0, __float_as_int(v), CTRL, 0xF, 0xF, true));
}
#define DPP_XOR1   0xB1
#define DPP_XOR2   0x4E
#define DPP_ROT1   0x93   // quad rotate: dest q <- (q-1)&3
#define DPP_HMIRR  0x141
#define DPP_MIRR   0x140

__device__ __forceinline__ int swzc(int k) { return k + ((k >> 5) << 2); }

#define A_BB 16
#define POISON32 0xAAAAAAAAu

// ---------------------------------------------------------------------------
// Stage A (unchanged known-good). 512 threads = 8 waves.
// ---------------------------------------------------------------------------
__global__ __launch_bounds__(512, 2) void lstm_e1_kernel(
    const float* __restrict__ x,     // [4096][140]
    const float* __restrict__ Wih,   // [512][1]
    const float* __restrict__ Whh,   // [512][128]
    const float* __restrict__ bih,   // [512]
    const float* __restrict__ bhh,   // [512]
    float* __restrict__ h1_out)      // [4096][128]
{
  const int j    = threadIdx.x;
  const int lane = j & 63;
  const int w    = j >> 6;
  const int u    = w * 16 + (lane >> 2);  // 0..127
  const int q    = lane & 3;
  const int b0   = blockIdx.x * A_BB;

  __shared__ float Hs[2][A_BB][144];
  __shared__ float xs[2][A_BB];

  for (int i = j; i < A_BB * 144; i += 512) ((float*)Hs[0])[i] = 0.0f;
  if (j < A_BB) xs[0][j] = x[(b0 + j) * 140];

  v2f wr2[4][16];
#pragma unroll
  for (int g = 0; g < 4; ++g)
#pragma unroll
    for (int k = 0; k < 32; k += 4) {
      const float4 t4 = *(const float4*)&Whh[(g * 128 + u) * 128 + q * 32 + k];
      wr2[g][k / 2 + 0].x = t4.x; wr2[g][k / 2 + 0].y = t4.y;
      wr2[g][k / 2 + 1].x = t4.z; wr2[g][k / 2 + 1].y = t4.w;
    }

  float wih[4], bs[4];
#pragma unroll
  for (int g = 0; g < 4; ++g) {
    wih[g] = Wih[g * 128 + u];
    bs[g]  = bih[g * 128 + u] + bhh[g * 128 + u];
  }

  float c[4]  = {0.f, 0.f, 0.f, 0.f};
  float hr[4] = {0.f, 0.f, 0.f, 0.f};
  __syncthreads();

  int cur = 0;
  for (int t = 0; t < 140; ++t) {
    const int nxt = cur ^ 1;

    v2f R2[4][4];
#pragma unroll
    for (int g = 0; g < 4; ++g)
#pragma unroll
      for (int i = 0; i < 4; ++i) { R2[g][i].x = 0.f; R2[g][i].y = 0.f; }

#pragma unroll
    for (int s = 0; s < 4; ++s) {
      if (s) {
#pragma unroll
        for (int g = 0; g < 4; ++g)
#pragma unroll
          for (int i = 0; i < 4; ++i) {
            R2[g][i].x = dppmv<DPP_ROT1>(R2[g][i].x);
            R2[g][i].y = dppmv<DPP_ROT1>(R2[g][i].y);
          }
      }
      const int cch = (q - 1 - s) & 3;
      const float* hbase = &Hs[cur][cch * 4][q * 36];
#pragma unroll
      for (int i = 0; i < 4; ++i) {
        const float* hrow = hbase + i * 144;
#pragma unroll
        for (int kk = 0; kk < 8; ++kk) {
          const float4 hv = *(const float4*)&hrow[kk * 4];
          v2f h01; h01.x = hv.x; h01.y = hv.y;
          v2f h23; h23.x = hv.z; h23.y = hv.w;
#pragma unroll
          for (int g = 0; g < 4; ++g) {
            R2[g][i] = pk_fma(wr2[g][2 * kk + 0], h01, R2[g][i]);
            R2[g][i] = pk_fma(wr2[g][2 * kk + 1], h23, R2[g][i]);
          }
        }
      }
    }

    if (j < A_BB && (t + 1) < 140) xs[nxt][j] = x[(b0 + j) * 140 + t + 1];

    const float4 xv = *(const float4*)&xs[cur][q * 4];
    const float xa[4] = {xv.x, xv.y, xv.z, xv.w};
#pragma unroll
    for (int i = 0; i < 4; ++i) {
      const float gi = sigm(R2[0][i].x + R2[0][i].y + __builtin_fmaf(wih[0], xa[i], bs[0]));
      const float gf = sigm(R2[1][i].x + R2[1][i].y + __builtin_fmaf(wih[1], xa[i], bs[1]));
      const float gg = tanh_fast(R2[2][i].x + R2[2][i].y + __builtin_fmaf(wih[2], xa[i], bs[2]));
      const float go = sigm(R2[3][i].x + R2[3][i].y + __builtin_fmaf(wih[3], xa[i], bs[3]));
      c[i]  = gf * c[i] + gi * gg;
      hr[i] = go * tanh_fast(c[i]);
      Hs[nxt][q * 4 + i][swzc(u)] = hr[i];
    }
    wg_barrier();
    cur = nxt;
  }

#pragma unroll
  for (int i = 0; i < 4; ++i)
    h1_out[(b0 + q * 4 + i) * 128 + u] = hr[i];
}

// ---------------------------------------------------------------------------
// Stage B input projection, PERMUTED: Up[t][u] = (pre_i,pre_f,pre_g,pre_o).
// ---------------------------------------------------------------------------
__global__ __launch_bounds__(256, 1) void u_pre_kernel(
    const float* __restrict__ h1,   // [4096][128]
    const float* __restrict__ Wih,  // [256][128]
    const float* __restrict__ bih,  // [256]
    const float* __restrict__ bhh,  // [256]
    float* __restrict__ Up)         // [4096][64][4]
{
  const int t = blockIdx.x;
  const int j = threadIdx.x;      // gate row j = g*64 + u
  __shared__ float hs[128];
  if (j < 128) hs[j] = h1[t * 128 + j];
  __syncthreads();
  float acc = bih[j] + bhh[j];
#pragma unroll
  for (int k = 0; k < 128; k += 4) {
    const float4 hv = *(const float4*)&hs[k];
    const float4 wv = *(const float4*)&Wih[j * 128 + k];
    acc += wv.x * hv.x + wv.y * hv.y + wv.z * hv.z + wv.w * hv.w;
  }
  Up[t * 256 + (j & 63) * 4 + (j >> 6)] = acc;
}

// ---------------------------------------------------------------------------
// Fused scan (waves 0-1, round-7 exact) + dec (all 8 waves, round-5 layout),
// covered by low-duty-cycle burner workgroups on all other CUs.
// ---------------------------------------------------------------------------
__global__ __launch_bounds__(512, 1) void scan_dec_kernel(
    const float4* __restrict__ Up,   // [4096][64] of (i,f,g,o)
    const float* __restrict__ WhhB,  // [256][64]
    const float* __restrict__ Wih1,  // [512][64]
    const float* __restrict__ Whh1,  // [512][128]
    const float* __restrict__ bih1,  // [512]
    const float* __restrict__ bhh1,  // [512]
    const float* __restrict__ Wih2,  // [4][128]
    const float* __restrict__ Whh2,  // [4][1]
    const float* __restrict__ bih2,  // [4]
    const float* __restrict__ bhh2,  // [4]
    float* __restrict__ out,         // [140]
    unsigned* __restrict__ flag)
{
  const int j = threadIdx.x;

  if (blockIdx.x != 0) {
    // ---- burner: ~3% duty cycle. Keeps a wave resident on every CU so the
    // clock governor boosts, without pulling enough power to hit the cap.
    // Exit condition is ABSOLUTE (flag != poison) so late-started burners
    // exit immediately — no deadlock regardless of dispatch order.
    float acc = (float)j;
    for (;;) {
#pragma unroll
      for (int i = 0; i < 16; ++i) acc = __builtin_fmaf(acc, 1.0000001f, 1.0f);
      asm volatile("" :: "v"(acc));
      __builtin_amdgcn_s_sleep(16);  // ~1024 cyc nap
      if (__hip_atomic_load(flag, __ATOMIC_RELAXED,
                            __HIP_MEMORY_SCOPE_AGENT) != POISON32) break;
    }
    return;
  }

  // ======================= workgroup 0 =====================================
  __shared__ float hb[2][64];
  __shared__ float zsd[64];
  __shared__ float hd[2][144];
  __shared__ float act4[4];

  if (j < 64) hb[0][j] = 0.0f;
  if (j < 144) hd[0][j] = 0.0f;
  __syncthreads();

  // ---------------- scan phase: waves 0-1 only (round-7 body) --------------
  if (j < 128) {
    const int u = j >> 1;   // 0..63
    const int p = j & 1;    // k-half

    v2f wr2[4][16];
#pragma unroll
    for (int g = 0; g < 4; ++g)
#pragma unroll
      for (int k = 0; k < 32; k += 4) {
        const float4 t4 = *(const float4*)&WhhB[(g * 64 + u) * 64 + p * 32 + k];
        wr2[g][k / 2 + 0].x = t4.x; wr2[g][k / 2 + 0].y = t4.y;
        wr2[g][k / 2 + 1].x = t4.z; wr2[g][k / 2 + 1].y = t4.w;
      }

    float c = 0.0f, h = 0.0f;
    float4 U0 = Up[0 * 64 + u];
    float4 U1 = Up[1 * 64 + u];

    int cur = 0;
#pragma unroll 1
    for (int t = 0; t < 4096; t += 2) {
#pragma unroll
      for (int half = 0; half < 2; ++half) {
        const int tp = (t + 2 + half < 4096) ? (t + 2 + half) : 4095;
        const float4 Unew = Up[tp * 64 + u];
        const float4 Ucur = half ? U1 : U0;

        const float* hrow = &hb[cur][p * 32];
        v2f A0, A1, A2, A3;
        A0.x = 0.f; A0.y = 0.f; A1 = A0; A2 = A0; A3 = A0;
#pragma unroll
        for (int kk = 0; kk < 8; ++kk) {
          const float4 hv = *(const float4*)&hrow[kk * 4];
          v2f hx; hx.x = hv.x; hx.y = hv.y;
          v2f hy; hy.x = hv.z; hy.y = hv.w;
          A0 = pk_fma(wr2[0][2 * kk], hx, A0); A0 = pk_fma(wr2[0][2 * kk + 1], hy, A0);
          A1 = pk_fma(wr2[1][2 * kk], hx, A1); A1 = pk_fma(wr2[1][2 * kk + 1], hy, A1);
          A2 = pk_fma(wr2[2][2 * kk], hx, A2); A2 = pk_fma(wr2[2][2 * kk + 1], hy, A2);
          A3 = pk_fma(wr2[3][2 * kk], hx, A3); A3 = pk_fma(wr2[3][2 * kk + 1], hy, A3);
        }
        float a0 = A0.x + A0.y, a1 = A1.x + A1.y;
        float a2 = A2.x + A2.y, a3 = A3.x + A3.y;
        a0 += dppmv<DPP_XOR1>(a0);
        a1 += dppmv<DPP_XOR1>(a1);
        a2 += dppmv<DPP_XOR1>(a2);
        a3 += dppmv<DPP_XOR1>(a3);

        const float gi = sigm(a0 + Ucur.x);
        const float gf = sigm(a1 + Ucur.y);
        const float gg = tanh_fast(a2 + Ucur.z);
        const float go = sigm(a3 + Ucur.w);
        c = gf * c + gi * gg;
        h = go * tanh_fast(c);
        if (p == 0) hb[cur ^ 1][u] = h;
        if (half) U1 = Unew; else U0 = Unew;
        wg_barrier();
        cur ^= 1;
      }
    }
    if (p == 0) zsd[u] = h;
  } else {
    // waves 2-7: barrier-matching idle loop (4096 barriers)
#pragma unroll 1
    for (int t = 0; t < 4096; ++t) wg_barrier();
  }
  __syncthreads();

  // ---------------- dec phase: all 8 waves (round-5 layout) ----------------
  const int u = j >> 2;   // 0..127
  const int q = j & 3;

  float wr[4][32];
#pragma unroll
  for (int g = 0; g < 4; ++g)
#pragma unroll
    for (int k = 0; k < 32; k += 4)
      *(float4*)&wr[g][k] = *(const float4*)&Whh1[(g * 128 + u) * 128 + q * 32 + k];

  float pre0[4];
#pragma unroll
  for (int g = 0; g < 4; ++g) {
    float acc = bih1[g * 128 + u] + bhh1[g * 128 + u];
#pragma unroll
    for (int k = 0; k < 64; k += 4) {
      const float4 zv = *(const float4*)&zsd[k];
      const float4 wv = *(const float4*)&Wih1[(g * 128 + u) * 64 + k];
      acc += wv.x * zv.x + wv.y * zv.y + wv.z * zv.z + wv.w * zv.w;
    }
    pre0[g] = acc;
  }

  const int g2  = j >> 4;
  const int i16 = j & 15;
  float w2d[8] = {0,0,0,0,0,0,0,0};
  if (j < 64) {
#pragma unroll
    for (int e = 0; e < 8; ++e) w2d[e] = Wih2[g2 * 128 + i16 * 8 + e];
  }
  const float bb2_0 = bih2[0] + bhh2[0], wh2_0 = Whh2[0];
  const float bb2_1 = bih2[1] + bhh2[1], wh2_1 = Whh2[1];
  const float bb2_2 = bih2[2] + bhh2[2], wh2_2 = Whh2[2];
  const float bb2_3 = bih2[3] + bhh2[3], wh2_3 = Whh2[3];

  float c1 = 0.0f;
  float c2 = 0.0f, h2 = 0.0f;

  int cur = 0;
  for (int t = 0; t < 140; ++t) {
    float a0 = 0.f, a1 = 0.f, a2 = 0.f, a3 = 0.f;
#pragma unroll
    for (int kk = 0; kk < 8; ++kk) {
      const float4 hv = *(const float4*)&hd[cur][q * 36 + kk * 4];
      a0 = __builtin_fmaf(wr[0][kk*4+0], hv.x, a0); a0 = __builtin_fmaf(wr[0][kk*4+1], hv.y, a0);
      a0 = __builtin_fmaf(wr[0][kk*4+2], hv.z, a0); a0 = __builtin_fmaf(wr[0][kk*4+3], hv.w, a0);
      a1 = __builtin_fmaf(wr[1][kk*4+0], hv.x, a1); a1 = __builtin_fmaf(wr[1][kk*4+1], hv.y, a1);
      a1 = __builtin_fmaf(wr[1][kk*4+2], hv.z, a1); a1 = __builtin_fmaf(wr[1][kk*4+3], hv.w, a1);
      a2 = __builtin_fmaf(wr[2][kk*4+0], hv.x, a2); a2 = __builtin_fmaf(wr[2][kk*4+1], hv.y, a2);
      a2 = __builtin_fmaf(wr[2][kk*4+2], hv.z, a2); a2 = __builtin_fmaf(wr[2][kk*4+3], hv.w, a2);
      a3 = __builtin_fmaf(wr[3][kk*4+0], hv.x, a3); a3 = __builtin_fmaf(wr[3][kk*4+1], hv.y, a3);
      a3 = __builtin_fmaf(wr[3][kk*4+2], hv.z, a3); a3 = __builtin_fmaf(wr[3][kk*4+3], hv.w, a3);
    }
    a0 += dppmv<DPP_XOR1>(a0); a0 += dppmv<DPP_XOR2>(a0);
    a1 += dppmv<DPP_XOR1>(a1); a1 += dppmv<DPP_XOR2>(a1);
    a2 += dppmv<DPP_XOR1>(a2); a2 += dppmv<DPP_XOR2>(a2);
    a3 += dppmv<DPP_XOR1>(a3); a3 += dppmv<DPP_XOR2>(a3);

    const float gi = sigm(a0 + pre0[0]);
    const float gf = sigm(a1 + pre0[1]);
    const float gg = tanh_fast(a2 + pre0[2]);
    const float go = sigm(a3 + pre0[3]);
    c1 = gf * c1 + gi * gg;
    const float h1v = go * tanh_fast(c1);
    if (q == 0) hd[cur ^ 1][swzc(u)] = h1v;
    wg_barrier();
    cur ^= 1;

    if (j < 64) {
      const int kb = i16 * 8;
      const float4 hA = *(const float4*)&hd[cur][swzc(kb)];
      const float4 hB = *(const float4*)&hd[cur][swzc(kb) + 4];
      float p = hA.x * w2d[0];
      p = __builtin_fmaf(hA.y, w2d[1], p);
      p = __builtin_fmaf(hA.z, w2d[2], p);
      p = __builtin_fmaf(hA.w, w2d[3], p);
      p = __builtin_fmaf(hB.x, w2d[4], p);
      p = __builtin_fmaf(hB.y, w2d[5], p);
      p = __builtin_fmaf(hB.z, w2d[6], p);
      p = __builtin_fmaf(hB.w, w2d[7], p);
      p += dppmv<DPP_XOR1>(p);
      p += dppmv<DPP_XOR2>(p);
      p += dppmv<DPP_HMIRR>(p);
      p += dppmv<DPP_MIRR>(p);
      if (i16 == 0) act4[g2] = p;
      const float4 acts = *(const float4*)&act4[0];  // same-wave, lgkm-ordered
      const float gi2 = sigm(acts.x + bb2_0 + wh2_0 * h2);
      const float gf2 = sigm(acts.y + bb2_1 + wh2_1 * h2);
      const float gg2 = tanh_fast(acts.z + bb2_2 + wh2_2 * h2);
      const float go2 = sigm(acts.w + bb2_3 + wh2_3 * h2);
      c2 = gf2 * c2 + gi2 * gg2;
      h2 = go2 * tanh_fast(c2);
      if (j == 0) out[t] = h2;
    }
  }

  // release burners (absolute sentinel: anything != poison)
  __threadfence();
  if (j == 0)
    __hip_atomic_store(flag, 0u, __ATOMIC_RELEASE, __HIP_MEMORY_SCOPE_AGENT);
}

// ---------------------------------------------------------------------------
extern "C" void kernel_launch(void* const* d_in, const int* in_sizes, int n_in,
                              void* d_out, int out_size, void* d_ws, size_t ws_size,
                              hipStream_t stream) {
  const float* x      = (const float*)d_in[0];
  const float* Wih_e1 = (const float*)d_in[1];
  const float* Whh_e1 = (const float*)d_in[2];
  const float* bih_e1 = (const float*)d_in[3];
  const float* bhh_e1 = (const float*)d_in[4];
  const float* Wih_e2 = (const float*)d_in[5];
  const float* Whh_e2 = (const float*)d_in[6];
  const float* bih_e2 = (const float*)d_in[7];
  const float* bhh_e2 = (const float*)d_in[8];
  const float* Wih_d1 = (const float*)d_in[9];
  const float* Whh_d1 = (const float*)d_in[10];
  const float* bih_d1 = (const float*)d_in[11];
  const float* bhh_d1 = (const float*)d_in[12];
  const float* Wih_d2 = (const float*)d_in[13];
  const float* Whh_d2 = (const float*)d_in[14];
  const float* bih_d2 = (const float*)d_in[15];
  const float* bhh_d2 = (const float*)d_in[16];

  float* out = (float*)d_out;  // 140 floats

  float* h1 = (float*)d_ws;              // 4096*128
  float* Up = h1 + 4096 * 128;           // 4096*256 (permuted [t][u][gate])
  unsigned* flag = (unsigned*)(Up + 4096 * 256);

  lstm_e1_kernel<<<4096 / A_BB, 512, 0, stream>>>(x, Wih_e1, Whh_e1, bih_e1, bhh_e1, h1);
  u_pre_kernel<<<4096, 256, 0, stream>>>(h1, Wih_e2, bih_e2, bhh_e2, Up);
  scan_dec_kernel<<<256, 512, 0, stream>>>((const float4*)Up, Whh_e2,
                                           Wih_d1, Whh_d1, bih_d1, bhh_d1,
                                           Wih_d2, Whh_d2, bih_d2, bhh_d2,
                                           out, flag);
}